// Round 19
// baseline (76.577 us; speedup 1.0000x reference)
//
#include <hip/hip_runtime.h>

// GCNBlock: out = relu( D^-1/2 (A+I) D^-1/2 (x@W) + b )
// N=50000, E=800000, D=64, fp32.
// R19: binsort scan -> shfl_up wave-scan + cross-wave combine (20 barriers ->
// 2 per block); bstart dropped (recomputed at dump, -4KB LDS); desc packed
// into u32 (start<<12|len; E<2^20, len<=2048) halving desc traffic; gather
// at 512 threads/block. Rest frozen from R18 (76.1us).

#define TPB 256
#define STPB 512      // fused kernel + gather block size
#define MAXDEG 64
#define OVFCAP 8192
#define EPB 2048      // edges per binsort block
#define MAXBIN 1024   // supports n <= 65536
#define MAXBLK 512    // supports E <= 1M (512*2048)
#define LUTSZ 2048    // j->segment LUT entries

typedef float fvec4 __attribute__((ext_vector_type(4)));  // nontemporal-safe

// ---- per-wave edge dtype detection --------------------------------------
// int64 little-endian with values <2^31 => every odd 32-bit word is 0.
__device__ __forceinline__ int edges_are_i32(const unsigned* __restrict__ w) {
    int lane = threadIdx.x & 63;
    unsigned v = w[1 + 2 * lane];
    return __ballot(v != 0u) != 0ull;
}

__device__ __forceinline__ unsigned short f2bf(float f) {  // RNE to bf16
    unsigned u = __float_as_uint(f);
    u += 0x7FFFu + ((u >> 16) & 1u);
    return (unsigned short)(u >> 16);
}
__device__ __forceinline__ float bf2f(unsigned short h) {
    return __uint_as_float(((unsigned)h) << 16);
}
__device__ __forceinline__ unsigned scale2(unsigned v, float dd) {  // 2 bf16
    unsigned lo = (unsigned)f2bf(dd * bf2f((unsigned short)(v & 0xFFFFu)));
    unsigned hi = (unsigned)f2bf(dd * bf2f((unsigned short)(v >> 16)));
    return lo | (hi << 16);
}

__device__ __forceinline__ void load4(const void* ei, int is32, long long base, int* v) {
    if (is32) {
        int4 a = *(const int4*)((const int*)ei + base);
        v[0] = a.x; v[1] = a.y; v[2] = a.z; v[3] = a.w;
    } else {
        longlong4 a = *(const longlong4*)((const long long*)ei + base);
        v[0] = (int)a.x; v[1] = (int)a.y; v[2] = (int)a.z; v[3] = (int)a.w;
    }
}

// ---- fused: gemm z0=bf16(x@W) (blocks < gemmBlocks) || binsort (rest) ---
// desc entry: (globalStart << 12) | len   [E < 2^20, len <= 2048]
__global__ __launch_bounds__(512) void gemm_binsort(
        const float* __restrict__ x, const float* __restrict__ W,
        unsigned short* __restrict__ z0, unsigned* __restrict__ ovf,
        const void* __restrict__ ei, unsigned* __restrict__ arena,
        unsigned* __restrict__ desc, int E, int nbins, int nblocks,
        int n, int gemmBlocks) {
    __shared__ __align__(16) unsigned char smem[16416];  // max(16KB gemm, 16.1KB sort)
    const int t = threadIdx.x;

    if ((int)blockIdx.x < gemmBlocks) {
        // ---- gemm: LDS-staged W; lane = column; 8 waves x 8 rows ----
        if (blockIdx.x == 0 && t == 0) *ovf = 0u;
        float* lw = (float*)smem;  // W[k*64+c], 16 KB
#pragma unroll
        for (int i = 0; i < 8; ++i) lw[i * 512 + t] = W[i * 512 + t];
        __syncthreads();

        const int lane = t & 63;
        const int wv   = t >> 6;                  // 0..7
        const int row0 = blockIdx.x * 64 + wv * 8;
        if (row0 >= n) return;  // wave-uniform
        const int nr = (n - row0 >= 8) ? 8 : (n - row0);

        float acc[8] = {0.f, 0.f, 0.f, 0.f, 0.f, 0.f, 0.f, 0.f};
#pragma unroll
        for (int k0 = 0; k0 < 16; ++k0) {
            const float w0 = lw[(4 * k0 + 0) * 64 + lane];
            const float w1 = lw[(4 * k0 + 1) * 64 + lane];
            const float w2 = lw[(4 * k0 + 2) * 64 + lane];
            const float w3 = lw[(4 * k0 + 3) * 64 + lane];
#pragma unroll
            for (int r = 0; r < 8; ++r) {
                if (r < nr) {
                    float4 xv = *(const float4*)(x + (long long)(row0 + r) * 64 + 4 * k0);
                    acc[r] = fmaf(xv.w, w3, fmaf(xv.z, w2, fmaf(xv.y, w1,
                             fmaf(xv.x, w0, acc[r]))));
                }
            }
        }
#pragma unroll
        for (int r = 0; r < 8; ++r)
            if (r < nr) z0[(long long)(row0 + r) * 64 + lane] = f2bf(acc[r]);
        return;
    }

    // ---- binsort: LDS counting sort of 2048 edges by dst>>6 ----
    unsigned* hist   = (unsigned*)smem;            // [MAXBIN]
    unsigned* cur    = hist + MAXBIN;              // [MAXBIN]
    unsigned* sorted = cur + MAXBIN;               // [EPB]
    unsigned* wsum   = sorted + EPB;               // [8]
    const int blk = (int)blockIdx.x - gemmBlocks;
    const long long base = (long long)blk * EPB;
    const int cnt = (int)((E - base < EPB) ? (E - base) : EPB);
    const int is32 = edges_are_i32((const unsigned*)ei);
    const int lane = t & 63;
    const int wid  = t >> 6;

    for (int i = t; i < nbins; i += STPB) hist[i] = 0u;
    __syncthreads();

    unsigned pay[4];
    unsigned short bn[4];
    {
        const int lo = t * 4;
        if (lo + 4 <= cnt) {
            int s4[4], d4[4];
            load4(ei, is32, base + lo, s4);
            load4(ei, is32, (long long)E + base + lo, d4);
#pragma unroll
            for (int k = 0; k < 4; ++k) {
                pay[k] = ((unsigned)(d4[k] & 63) << 16) | (unsigned)s4[k];
                bn[k]  = (unsigned short)((unsigned)d4[k] >> 6);
                atomicAdd(&hist[bn[k]], 1u);
            }
        } else {
#pragma unroll
            for (int k = 0; k < 4; ++k) {
                int l = lo + k;
                if (l < cnt) {
                    int s_, d_;
                    if (is32) {
                        s_ = ((const int*)ei)[base + l];
                        d_ = ((const int*)ei)[(long long)E + base + l];
                    } else {
                        s_ = (int)((const long long*)ei)[base + l];
                        d_ = (int)((const long long*)ei)[(long long)E + base + l];
                    }
                    pay[k] = ((unsigned)(d_ & 63) << 16) | (unsigned)s_;
                    bn[k]  = (unsigned short)((unsigned)d_ >> 6);
                    atomicAdd(&hist[bn[k]], 1u);
                } else {
                    bn[k] = 0xFFFFu;  // invalid sentinel
                }
            }
        }
    }
    __syncthreads();

    // exclusive prefix over nbins: per-thread 2-bin sum, shfl wave-scan,
    // cross-wave combine (2 barriers total)
    const int bq0 = t * 2, bq1 = t * 2 + 1;
    unsigned h0 = (bq0 < nbins) ? hist[bq0] : 0u;
    unsigned h1 = (bq1 < nbins) ? hist[bq1] : 0u;
    unsigned s0 = h0 + h1;
    unsigned xsc = s0;
#pragma unroll
    for (int o = 1; o < 64; o <<= 1) {
        unsigned v = (unsigned)__shfl_up((int)xsc, o);
        if (lane >= o) xsc += v;
    }
    if (lane == 63) wsum[wid] = xsc;
    __syncthreads();
    unsigned woff = 0;
#pragma unroll
    for (int w = 0; w < 8; ++w) woff += (w < wid) ? wsum[w] : 0u;
    const unsigned excl = xsc + woff - s0;   // exclusive start of bq0
    if (bq0 < nbins) cur[bq0] = excl;
    if (bq1 < nbins) cur[bq1] = excl + h0;
    __syncthreads();

    // LDS scatter into bin order
#pragma unroll
    for (int i = 0; i < 4; ++i) {
        if (bn[i] != 0xFFFFu) {
            unsigned p = atomicAdd(&cur[bn[i]], 1u);
            sorted[p] = pay[i];
        }
    }
    __syncthreads();

    // coalesced arena dump + contiguous packed-descriptor dump
    for (int i = t; i < cnt; i += STPB) arena[base + i] = sorted[i];
    for (int bq = t; bq < nbins; bq += STPB) {
        unsigned len   = hist[bq];
        unsigned start = cur[bq] - len;        // post-scatter cur = start+len
        desc[(long long)blk * nbins + bq] =
            (((unsigned)base + start) << 12) | len;
    }
}

// ---- build_ell: per-bin segment stitch -> LDS ELL -> coalesced dump -----
// j->segment via LDS LUT (2 LDS reads/edge; binary-search fallback j>=LUTSZ).
__global__ __launch_bounds__(256) void build_ell(const unsigned* __restrict__ desc,
                                                 const unsigned* __restrict__ arena,
                                                 unsigned* __restrict__ fc,
                                                 unsigned short* __restrict__ ell,
                                                 unsigned* __restrict__ ovf,
                                                 int* __restrict__ ovfList,
                                                 unsigned short* __restrict__ z,
                                                 int n, int nbins, int nblocks) {
    __shared__ unsigned segstart[MAXBLK];
    __shared__ unsigned segpre[MAXBLK];
    __shared__ unsigned pre[MAXBLK];
    __shared__ unsigned lcnt[MAXDEG];
    __shared__ unsigned short lut[LUTSZ];                           // 4 KB
    __shared__ __align__(16) unsigned short lell[MAXDEG * MAXDEG];  // 8 KB
    const int t   = threadIdx.x;
    const int bin = blockIdx.x;
    const int base = bin * MAXDEG;

    if (t < MAXDEG) lcnt[t] = 0u;

    unsigned len0 = 0, len1 = 0;
    if (t < nblocks) {
        unsigned dd = desc[(long long)t * nbins + bin];
        segstart[t] = dd >> 12;
        len0 = dd & 0xFFFu;
    }
    if (t + 256 < nblocks) {
        unsigned dd = desc[(long long)(t + 256) * nbins + bin];
        segstart[t + 256] = dd >> 12;
        len1 = dd & 0xFFFu;
    }
    pre[t] = len0;
    pre[t + 256] = len1;
    __syncthreads();
    // scan both 256-halves simultaneously, then offset the upper half
    for (int o = 1; o < 256; o <<= 1) {
        unsigned vA = (t >= o) ? pre[t - o] : 0u;
        unsigned vB = (t >= o) ? pre[256 + t - o] : 0u;
        __syncthreads();
        pre[t] += vA;
        pre[256 + t] += vB;
        __syncthreads();
    }
    const unsigned lowTot = pre[255];
    pre[256 + t] += lowTot;   // no thread writes pre[255] here
    __syncthreads();
    const unsigned total = pre[MAXBLK - 1];
    unsigned sp0 = 0, sp1 = 0;
    if (t < nblocks) { sp0 = pre[t] - len0; segpre[t] = sp0; }
    if (t + 256 < nblocks) { sp1 = pre[256 + t] - len1; segpre[t + 256] = sp1; }
    __syncthreads();

    // fill j->segment LUT (each thread writes its own segments' spans)
    for (unsigned k = 0; k < len0 && sp0 + k < LUTSZ; ++k)
        lut[sp0 + k] = (unsigned short)t;
    for (unsigned k = 0; k < len1 && sp1 + k < LUTSZ; ++k)
        lut[sp1 + k] = (unsigned short)(t + 256);
    __syncthreads();

    for (unsigned j = t; j < total; j += 256) {
        int lo;
        if (j < LUTSZ) {
            lo = (int)lut[j];
        } else {  // fallback: largest k with segpre[k] <= j
            int l = 0, hi = nblocks - 1;
            while (l < hi) {
                int mid = (l + hi + 1) >> 1;
                if (segpre[mid] <= j) l = mid; else hi = mid - 1;
            }
            lo = l;
        }
        unsigned e  = arena[segstart[lo] + (j - segpre[lo])];
        unsigned dl = e >> 16;
        unsigned c  = atomicAdd(&lcnt[dl], 1u);
        if (c < MAXDEG) {
            lell[dl * MAXDEG + c] = (unsigned short)(e & 0xFFFFu);
        } else {  // deg > 64: exact deg kept in lcnt; extra edge via ovfList
            unsigned p = atomicAdd(ovf, 1u);
            if (p < OVFCAP) {
                ovfList[2 * p]     = (int)(e & 0xFFFFu);
                ovfList[2 * p + 1] = base + (int)dl;
            }
        }
    }
    __syncthreads();

    const int maxrow = (n - base < MAXDEG) ? (n - base) : MAXDEG;
    if (t < maxrow) fc[base + t] = lcnt[t];

    // coalesced ELL dump: maxrow rows x 128B (8 uint4 per row)
    const uint4* lp = (const uint4*)lell;
    uint4* gp = (uint4*)(ell + (long long)base * MAXDEG);
    for (int i = t; i < maxrow * 8; i += 256) gp[i] = lp[i];

    // scale z rows in place: z[row] *= rsqrt(1 + deg)
    uint4* zp = (uint4*)(z + (long long)base * 64);
    for (int i = t; i < maxrow * 8; i += 256) {
        int row = i >> 3;
        float dd = rsqrtf(1.0f + (float)lcnt[row]);
        uint4 v = zp[i];
        v.x = scale2(v.x, dd); v.y = scale2(v.y, dd);
        v.z = scale2(v.z, dd); v.w = scale2(v.w, dd);
        zp[i] = v;
    }
}

// ---- gather: 8 nodes/wave; lane owns 8 channels (uint4 16B loads) -------
// out = relu( dd * (z[node] + sum z[nbr]) + b ), nontemporal out stores.
__global__ __launch_bounds__(512) void gather_z(const unsigned short* __restrict__ ell,
                                                const unsigned* __restrict__ fc,
                                                const unsigned* __restrict__ ovf,
                                                const int* __restrict__ ovfList,
                                                const unsigned short* __restrict__ z,
                                                const float* __restrict__ b,
                                                float* __restrict__ out, int n) {
    const int wv   = (int)threadIdx.x >> 6;
    const int lane = threadIdx.x & 63;
    const int o    = lane >> 3;       // octant -> which node of the eight
    const int cp   = lane & 7;        // channel octet (8 bf16 = 1 uint4)
    const int node = (blockIdx.x * 8 + wv) * 8 + o;
    const bool valid = node < n;
    const int nodec = valid ? node : (n - 1);  // clamped for safe addressing

    const unsigned deg = valid ? fc[nodec] : 0u;
    const float dd = rsqrtf(1.0f + (float)deg);

    uint4 zs = *(const uint4*)(z + (unsigned)nodec * 64 + cp * 8);
    float a0 = bf2f((unsigned short)(zs.x & 0xFFFFu));   // self-loop term
    float a1 = bf2f((unsigned short)(zs.x >> 16));
    float a2 = bf2f((unsigned short)(zs.y & 0xFFFFu));
    float a3 = bf2f((unsigned short)(zs.y >> 16));
    float a4 = bf2f((unsigned short)(zs.z & 0xFFFFu));
    float a5 = bf2f((unsigned short)(zs.z >> 16));
    float a6 = bf2f((unsigned short)(zs.w & 0xFFFFu));
    float a7 = bf2f((unsigned short)(zs.w >> 16));

    unsigned m = deg < MAXDEG ? deg : MAXDEG;
    if (!valid) m = 0u;
    unsigned mm = m;
    {   // wave-uniform trip count: max over the 8 octants
        unsigned q1 = (unsigned)__shfl_xor((int)mm, 8);  mm = mm > q1 ? mm : q1;
        unsigned q2 = (unsigned)__shfl_xor((int)mm, 16); mm = mm > q2 ? mm : q2;
        unsigned q3 = (unsigned)__shfl_xor((int)mm, 32); mm = mm > q3 ? mm : q3;
    }
    const unsigned mmax = mm;

    const uint4* prow = (const uint4*)(ell + (unsigned)nodec * MAXDEG);

    unsigned i = 0;
    for (; i + 8 <= mmax; i += 8) {
        uint4 rw = prow[i >> 3];      // per-octant broadcast of 8 ids
        unsigned s[8];
        s[0] = rw.x & 0xFFFFu; s[1] = rw.x >> 16;
        s[2] = rw.y & 0xFFFFu; s[3] = rw.y >> 16;
        s[4] = rw.z & 0xFFFFu; s[5] = rw.z >> 16;
        s[6] = rw.w & 0xFFFFu; s[7] = rw.w >> 16;
        if (i + 8 <= m) {             // full batch for this octant
            uint4 v[8];
#pragma unroll
            for (int k = 0; k < 8; ++k)
                v[k] = *(const uint4*)(z + s[k] * 64u + cp * 8);
#pragma unroll
            for (int k = 0; k < 8; ++k) {
                a0 += bf2f((unsigned short)(v[k].x & 0xFFFFu));
                a1 += bf2f((unsigned short)(v[k].x >> 16));
                a2 += bf2f((unsigned short)(v[k].y & 0xFFFFu));
                a3 += bf2f((unsigned short)(v[k].y >> 16));
                a4 += bf2f((unsigned short)(v[k].z & 0xFFFFu));
                a5 += bf2f((unsigned short)(v[k].z >> 16));
                a6 += bf2f((unsigned short)(v[k].w & 0xFFFFu));
                a7 += bf2f((unsigned short)(v[k].w >> 16));
            }
        } else {                      // partial batch (divergent tail)
#pragma unroll
            for (int k = 0; k < 8; ++k) {
                if (i + k < m) {
                    uint4 v = *(const uint4*)(z + s[k] * 64u + cp * 8);
                    a0 += bf2f((unsigned short)(v.x & 0xFFFFu));
                    a1 += bf2f((unsigned short)(v.x >> 16));
                    a2 += bf2f((unsigned short)(v.y & 0xFFFFu));
                    a3 += bf2f((unsigned short)(v.y >> 16));
                    a4 += bf2f((unsigned short)(v.z & 0xFFFFu));
                    a5 += bf2f((unsigned short)(v.z >> 16));
                    a6 += bf2f((unsigned short)(v.w & 0xFFFFu));
                    a7 += bf2f((unsigned short)(v.w >> 16));
                }
            }
        }
    }
    for (; i < mmax; ++i) {
        if (i < m) {
            unsigned s = ell[(unsigned)nodec * MAXDEG + i];
            uint4 v = *(const uint4*)(z + s * 64u + cp * 8);
            a0 += bf2f((unsigned short)(v.x & 0xFFFFu));
            a1 += bf2f((unsigned short)(v.x >> 16));
            a2 += bf2f((unsigned short)(v.y & 0xFFFFu));
            a3 += bf2f((unsigned short)(v.y >> 16));
            a4 += bf2f((unsigned short)(v.z & 0xFFFFu));
            a5 += bf2f((unsigned short)(v.z >> 16));
            a6 += bf2f((unsigned short)(v.w & 0xFFFFu));
            a7 += bf2f((unsigned short)(v.w >> 16));
        }
    }

    unsigned nov = *ovf;  // overflow edges: normally zero
    if (nov > 0) {
        nov = nov < OVFCAP ? nov : OVFCAP;
        for (unsigned j = 0; j < nov; ++j)
            if (valid && ovfList[2 * j + 1] == node) {
                uint4 v = *(const uint4*)(z + (unsigned)ovfList[2 * j] * 64u + cp * 8);
                a0 += bf2f((unsigned short)(v.x & 0xFFFFu));
                a1 += bf2f((unsigned short)(v.x >> 16));
                a2 += bf2f((unsigned short)(v.y & 0xFFFFu));
                a3 += bf2f((unsigned short)(v.y >> 16));
                a4 += bf2f((unsigned short)(v.z & 0xFFFFu));
                a5 += bf2f((unsigned short)(v.z >> 16));
                a6 += bf2f((unsigned short)(v.w & 0xFFFFu));
                a7 += bf2f((unsigned short)(v.w >> 16));
            }
    }

    if (valid) {
        float4 b0 = *(const float4*)(b + cp * 8);
        float4 b1 = *(const float4*)(b + cp * 8 + 4);
        fvec4 o0, o1;
        o0.x = fmaxf(fmaf(dd, a0, b0.x), 0.f);
        o0.y = fmaxf(fmaf(dd, a1, b0.y), 0.f);
        o0.z = fmaxf(fmaf(dd, a2, b0.z), 0.f);
        o0.w = fmaxf(fmaf(dd, a3, b0.w), 0.f);
        o1.x = fmaxf(fmaf(dd, a4, b1.x), 0.f);
        o1.y = fmaxf(fmaf(dd, a5, b1.y), 0.f);
        o1.z = fmaxf(fmaf(dd, a6, b1.z), 0.f);
        o1.w = fmaxf(fmaf(dd, a7, b1.w), 0.f);
        __builtin_nontemporal_store(o0, (fvec4*)(out + (unsigned)node * 64 + cp * 8));
        __builtin_nontemporal_store(o1, (fvec4*)(out + (unsigned)node * 64 + cp * 8 + 4));
    }
}

extern "C" void kernel_launch(void* const* d_in, const int* in_sizes, int n_in,
                              void* d_out, int out_size, void* d_ws, size_t ws_size,
                              hipStream_t stream) {
    const float* x  = (const float*)d_in[0];
    const void*  ei = d_in[1];
    const float* W  = (const float*)d_in[2];
    const float* b  = (const float*)d_in[3];
    float* out = (float*)d_out;

    const int n = in_sizes[0] / 64;   // 50000
    const int E = in_sizes[1] / 2;    // 800000  (< 2^20: desc packing valid)
    const int nbins   = (n + MAXDEG - 1) / MAXDEG;  // 782
    const int nblocks = (E + EPB - 1) / EPB;        // 391
    const int gemmBlocks = (n + 63) / 64;           // 782

    // ws: z[n*64] u16 (6.4M) | ell[n*64] u16 (6.4M) | fc[n] u32 (0.2M) |
    //     ovf u32 | ovfList[2*OVFCAP] (64K) | arena[E] u32 (3.2M) |
    //     desc[nblocks*nbins] u32 (1.23M)  => ~17.5MB (< proven 19.46MB)
    unsigned short* z       = (unsigned short*)d_ws;
    unsigned short* ell     = z + (long long)n * 64;
    unsigned*       fc      = (unsigned*)(ell + (long long)n * 64);
    unsigned*       ovf     = fc + n;
    int*            ovfList = (int*)(ovf + 1);
    unsigned*       arena   = (unsigned*)(ovfList + 2 * OVFCAP);
    unsigned*       desc    = arena + E;

    gemm_binsort<<<gemmBlocks + nblocks, STPB, 0, stream>>>(
        x, W, z, ovf, ei, arena, desc, E, nbins, nblocks, n, gemmBlocks);
    build_ell<<<nbins, TPB, 0, stream>>>(desc, arena, fc, ell, ovf, ovfList, z,
                                         n, nbins, nblocks);
    gather_z<<<(n + 63) / 64, STPB, 0, stream>>>(ell, fc, ovf, ovfList, z, b, out, n);
}